// Round 1
// baseline (278.880 us; speedup 1.0000x reference)
//
#include <hip/hip_runtime.h>
#include <math.h>

// Problem constants (from reference)
#define NN 50000   // nodes
#define RR 32      // relations
#define HH 16      // hidden
#define CC 8       // classes

// ---------------- kernels ----------------

// cnt[r*N + dst] += 1 per edge
__global__ void count_k(const int* __restrict__ et, const int* __restrict__ dst,
                        float* __restrict__ cnt, int E) {
    int stride = gridDim.x * blockDim.x;
    for (int i = blockIdx.x * blockDim.x + threadIdx.x; i < E; i += stride)
        atomicAdd(&cnt[et[i] * NN + dst[i]], 1.0f);
}

// cnt -> 1/max(cnt,1)
__global__ void inv_k(float* __restrict__ cnt, int n) {
    int i = blockIdx.x * blockDim.x + threadIdx.x;
    if (i < n) cnt[i] = 1.0f / fmaxf(cnt[i], 1.0f);
}

// layer 1: h[d*H + i] += weight1[r, s, i] * inv[r*N + d]
// one thread per (edge, channel); 16 consecutive lanes share an edge
__global__ void layer1_k(const int* __restrict__ src, const int* __restrict__ dst,
                         const int* __restrict__ et, const float* __restrict__ w1,
                         const float* __restrict__ inv, float* __restrict__ h, int E) {
    int total = E * HH;
    int stride = gridDim.x * blockDim.x;
    for (int t = blockIdx.x * blockDim.x + threadIdx.x; t < total; t += stride) {
        int e = t >> 4;
        int i = t & 15;
        int r = et[e], s = src[e], d = dst[e];
        float sc = inv[r * NN + d];
        float w  = w1[(r * NN + s) * HH + i];
        atomicAdd(&h[d * HH + i], w * sc);
    }
}

// h = relu(h + root1 + bias1)
__global__ void hfin_k(float* __restrict__ h, const float* __restrict__ root1,
                       const float* __restrict__ bias1) {
    int t = blockIdx.x * blockDim.x + threadIdx.x;
    if (t < NN * HH) h[t] = fmaxf(h[t] + root1[t] + bias1[t & 15], 0.0f);
}

// layer 2: out[d*C + c] += (sum_f h[s,f] * w2[r,f,c]) * inv[r*N + d]
// one thread per (edge, class); 8 consecutive lanes share an edge
__global__ void layer2_k(const int* __restrict__ src, const int* __restrict__ dst,
                         const int* __restrict__ et, const float* __restrict__ h,
                         const float* __restrict__ w2, const float* __restrict__ inv,
                         float* __restrict__ out, int E) {
    int total = E * CC;
    int stride = gridDim.x * blockDim.x;
    for (int t = blockIdx.x * blockDim.x + threadIdx.x; t < total; t += stride) {
        int e = t >> 3;
        int c = t & 7;
        int r = et[e], s = src[e], d = dst[e];
        float sc = inv[r * NN + d];
        const float* hs = &h[s * HH];
        const float* wr = &w2[r * HH * CC];
        float acc = 0.0f;
#pragma unroll
        for (int f = 0; f < HH; ++f) acc += hs[f] * wr[f * CC + c];
        atomicAdd(&out[d * CC + c], acc * sc);
    }
}

// out = log_softmax(out + h @ root2 + bias2), one thread per node
__global__ void ofin_k(float* __restrict__ out, const float* __restrict__ h,
                       const float* __restrict__ root2, const float* __restrict__ bias2) {
    int n = blockIdx.x * blockDim.x + threadIdx.x;
    if (n >= NN) return;
    float hv[HH];
#pragma unroll
    for (int f = 0; f < HH; ++f) hv[f] = h[n * HH + f];
    float v[CC];
#pragma unroll
    for (int c = 0; c < CC; ++c) {
        float acc = out[n * CC + c] + bias2[c];
#pragma unroll
        for (int f = 0; f < HH; ++f) acc += hv[f] * root2[f * CC + c];
        v[c] = acc;
    }
    float m = v[0];
#pragma unroll
    for (int c = 1; c < CC; ++c) m = fmaxf(m, v[c]);
    float s = 0.0f;
#pragma unroll
    for (int c = 0; c < CC; ++c) s += expf(v[c] - m);
    float l = logf(s);
#pragma unroll
    for (int c = 0; c < CC; ++c) out[n * CC + c] = v[c] - m - l;
}

// ---------------- launch ----------------

extern "C" void kernel_launch(void* const* d_in, const int* in_sizes, int n_in,
                              void* d_out, int out_size, void* d_ws, size_t ws_size,
                              hipStream_t stream) {
    const int*   edge_index = (const int*)d_in[0];   // (2, E)
    const int*   edge_type  = (const int*)d_in[1];   // (E,)
    const float* weight1    = (const float*)d_in[2]; // (R, N, H)
    const float* root1      = (const float*)d_in[3]; // (N, H)
    const float* bias1      = (const float*)d_in[4]; // (H,)
    const float* weight2    = (const float*)d_in[5]; // (R, H, C)
    const float* root2      = (const float*)d_in[6]; // (H, C)
    const float* bias2      = (const float*)d_in[7]; // (C,)
    float* out = (float*)d_out;

    const int E = in_sizes[1];
    const int* src = edge_index;
    const int* dst = edge_index + E;

    // workspace: cnt/inv [R*N] floats, h [N*H] floats
    float* cnt = (float*)d_ws;
    float* h   = cnt + (size_t)RR * NN;

    hipMemsetAsync(cnt, 0, sizeof(float) * (size_t)RR * NN, stream);
    hipMemsetAsync(h,   0, sizeof(float) * (size_t)NN * HH, stream);
    hipMemsetAsync(out, 0, sizeof(float) * (size_t)NN * CC, stream);

    const int B = 256;
    const int GRID_CAP = 2048;

    int g_cnt = min((E + B - 1) / B, GRID_CAP);
    count_k<<<g_cnt, B, 0, stream>>>(edge_type, dst, cnt, E);

    int n_inv = RR * NN;
    inv_k<<<(n_inv + B - 1) / B, B, 0, stream>>>(cnt, n_inv);

    int g_l1 = min((E * HH + B - 1) / B, GRID_CAP);
    layer1_k<<<g_l1, B, 0, stream>>>(src, dst, edge_type, weight1, cnt, h, E);

    hfin_k<<<(NN * HH + B - 1) / B, B, 0, stream>>>(h, root1, bias1);

    int g_l2 = min((E * CC + B - 1) / B, GRID_CAP);
    layer2_k<<<g_l2, B, 0, stream>>>(src, dst, edge_type, h, weight2, cnt, out, E);

    ofin_k<<<(NN + B - 1) / B, B, 0, stream>>>(out, h, root2, bias2);
}